// Round 4
// baseline (16462.569 us; speedup 1.0000x reference)
//
#include <hip/hip_runtime.h>

typedef _Float16 half8 __attribute__((ext_vector_type(8)));
typedef float floatx4 __attribute__((ext_vector_type(4)));

#define S_LEN 512
#define NB 64
#define NI 256
#define NR 2048
#define LEAK 0.9f

#define NBLK 128
#define TPB 512
#define FPB 32               /* features per block */
#define LBLK 64              /* blocks per layer */
#define NBNR ((size_t)NB * NR)

// ---- workspace offsets ----
#define OFF_BAR ((size_t)0)
#define OFF_H0  ((size_t)4096)
#define OFF_H1  (OFF_H0 + 2 * NBNR * 2)
#define OFF_XF  (OFF_H1 + 2 * NBNR * 2)

// x fp32 -> fp16, 8 elems/thread
__global__ void xconv_kernel(const float* __restrict__ x, _Float16* __restrict__ xf) {
    size_t i = ((size_t)blockIdx.x * 256 + threadIdx.x) * 8;
    const float4 a = *(const float4*)(x + i);
    const float4 b = *(const float4*)(x + i + 4);
    half8 v;
    v[0] = (_Float16)a.x; v[1] = (_Float16)a.y; v[2] = (_Float16)a.z; v[3] = (_Float16)a.w;
    v[4] = (_Float16)b.x; v[5] = (_Float16)b.y; v[6] = (_Float16)b.z; v[7] = (_Float16)b.w;
    *(half8*)(xf + i) = v;
}

__device__ __forceinline__ half8 cvt8(const float* s) {
    float4 p = *(const float4*)s, q = *(const float4*)(s + 4);
    half8 v;
    v[0] = (_Float16)p.x; v[1] = (_Float16)p.y; v[2] = (_Float16)p.z; v[3] = (_Float16)p.w;
    v[4] = (_Float16)q.x; v[5] = (_Float16)q.y; v[6] = (_Float16)q.z; v[7] = (_Float16)q.w;
    return v;
}

// L1/L2-bypassing 16B load (2 x 8B relaxed agent atomics -> read LLC directly)
__device__ __forceinline__ half8 ldA(const _Float16* p) {
    union { half8 v; unsigned long long q[2]; } u;
    u.q[0] = __hip_atomic_load((const unsigned long long*)p,
                               __ATOMIC_RELAXED, __HIP_MEMORY_SCOPE_AGENT);
    u.q[1] = __hip_atomic_load((const unsigned long long*)p + 1,
                               __ATOMIC_RELAXED, __HIP_MEMORY_SCOPE_AGENT);
    return u.v;
}

// write-through 2B publish (never dirty in L2)
__device__ __forceinline__ void stH(_Float16* p, _Float16 v) {
    unsigned short b;
    __builtin_memcpy(&b, &v, 2);
    __hip_atomic_store((unsigned short*)p, b, __ATOMIC_RELAXED, __HIP_MEMORY_SCOPE_AGENT);
}

// two-level grid barrier, NO cache-flushing fences (data goes via LLC-bypass ops).
// Root ACQ_REL + gen RELEASE order the counter resets before the gen flip.
__device__ __forceinline__ void gbar(unsigned* bar) {
    __syncthreads();                       // drains each wave's vmcnt (publishes done)
    if (threadIdx.x == 0) {
        unsigned* cnt  = bar + (blockIdx.x & 7) * 32;
        unsigned* root = bar + 256;
        unsigned* gen  = bar + 272;
        unsigned g = __hip_atomic_load(gen, __ATOMIC_RELAXED, __HIP_MEMORY_SCOPE_AGENT);
        bool last = false;
        if (__hip_atomic_fetch_add(cnt, 1u, __ATOMIC_RELAXED, __HIP_MEMORY_SCOPE_AGENT) == (NBLK / 8 - 1)) {
            __hip_atomic_store(cnt, 0u, __ATOMIC_RELAXED, __HIP_MEMORY_SCOPE_AGENT);
            if (__hip_atomic_fetch_add(root, 1u, __ATOMIC_ACQ_REL, __HIP_MEMORY_SCOPE_AGENT) == 7u) {
                __hip_atomic_store(root, 0u, __ATOMIC_RELAXED, __HIP_MEMORY_SCOPE_AGENT);
                __hip_atomic_store(gen, g + 1u, __ATOMIC_RELEASE, __HIP_MEMORY_SCOPE_AGENT);
                last = true;
            }
        }
        if (!last)
            while (__hip_atomic_load(gen, __ATOMIC_RELAXED, __HIP_MEMORY_SCOPE_AGENT) == g)
                __builtin_amdgcn_s_sleep(1);
    }
    __syncthreads();
}

// One layer, persistent. 8 waves; wave = K-slice owner (weights in VGPRs).
template <int CH, int KU, int ROLE>
__device__ __forceinline__ void esn_layer_run(
    const float* __restrict__ bias_v,
    const float* __restrict__ Whh, const float* __restrict__ Win,
    const _Float16* __restrict__ xf,   // ROLE 0: input sequence (cached reads ok)
    _Float16* __restrict__ hp,         // own h ping-pong (LLC-coherent traffic)
    _Float16* __restrict__ h0p,        // ROLE 1: producer (y0) ping-pong
    float* __restrict__ out,
    unsigned* __restrict__ bar,
    float* __restrict__ rsc, int r0)
{
    const int tid = threadIdx.x;
    const int l = tid & 63, wid = tid >> 6, l15 = l & 15, g = l >> 4;

    // ---- load this wave's K-slice of W into registers (once) ----
    half8 bwA[CH], bwB[CH];
    #pragma unroll
    for (int c = 0; c < CH; ++c) {
        const int k0 = (wid * CH + c) * 32 + g * 8;
        const float* s0 = (k0 < NR) ? Whh + (size_t)(r0 + l15) * NR + k0
                                    : Win + (size_t)(r0 + l15) * KU + (k0 - NR);
        const float* s1 = (k0 < NR) ? Whh + (size_t)(r0 + 16 + l15) * NR + k0
                                    : Win + (size_t)(r0 + 16 + l15) * KU + (k0 - NR);
        bwA[c] = cvt8(s0);
        bwB[c] = cvt8(s1);
    }

    const int fg_o = wid & 1, bt_o = wid >> 1;
    const int ncol = r0 + fg_o * 16 + l15;
    const int bj0 = bt_o * 16 + g * 4;
    const float bias = bias_v[ncol];
    float hs[4] = {0.f, 0.f, 0.f, 0.f};
    float* hn_base = out + (size_t)S_LEN * NBNR + (size_t)ROLE * NBNR;

    for (int s = 0; s < S_LEN + 1; ++s) {
        const int t = (ROLE == 0) ? s : s - 1;
        const bool active = (ROLE == 0) ? (s < S_LEN) : (s >= 1);
        if (active) {
            const _Float16* hrd = hp + (size_t)(t & 1) * NBNR;
            const _Float16* urd = (ROLE == 0)
                ? xf + (size_t)t * NB * NI
                : h0p + (size_t)((t + 1) & 1) * NBNR;

            floatx4 acc[2][4];
            #pragma unroll
            for (int fg = 0; fg < 2; ++fg)
                #pragma unroll
                for (int bt = 0; bt < 4; ++bt)
                    acc[fg][bt] = (floatx4){0.f, 0.f, 0.f, 0.f};

            #pragma unroll
            for (int bt = 0; bt < 4; ++bt) {
                const int row = bt * 16 + l15;
                // stage this bt's A-fragments: atomics issue back-to-back,
                // one waitcnt before the MFMA cluster
                half8 abuf[CH];
                #pragma unroll
                for (int c = 0; c < CH; ++c) {
                    const int KB32 = (wid * CH + c) * 32;
                    if (KB32 < NR) {
                        abuf[c] = ldA(hrd + (size_t)row * NR + KB32 + g * 8);
                    } else {
                        const _Float16* pu = urd + (size_t)row * KU + (KB32 - NR) + g * 8;
                        abuf[c] = (ROLE == 1) ? ldA(pu) : *(const half8*)pu;
                    }
                }
                #pragma unroll
                for (int c = 0; c < CH; ++c) {
                    acc[0][bt] = __builtin_amdgcn_mfma_f32_16x16x32_f16(abuf[c], bwA[c], acc[0][bt], 0, 0, 0);
                    acc[1][bt] = __builtin_amdgcn_mfma_f32_16x16x32_f16(abuf[c], bwB[c], acc[1][bt], 0, 0, 0);
                }
            }

            // cross-wave K reduction through LDS (contiguous 16B/lane, conflict-free)
            #pragma unroll
            for (int fg = 0; fg < 2; ++fg)
                #pragma unroll
                for (int bt = 0; bt < 4; ++bt)
                    *(floatx4*)(rsc + (size_t)((wid * 8 + fg * 4 + bt) * 64 + l) * 4) = acc[fg][bt];
            __syncthreads();

            floatx4 r = {0.f, 0.f, 0.f, 0.f};
            #pragma unroll
            for (int v = 0; v < 8; ++v)
                r += *(const floatx4*)(rsc + (size_t)((v * 8 + fg_o * 4 + bt_o) * 64 + l) * 4);

            _Float16* hwr = hp + (size_t)((t + 1) & 1) * NBNR;
            #pragma unroll
            for (int j = 0; j < 4; ++j) {
                float hn = (1.0f - LEAK) * hs[j] + LEAK * tanhf(r[j] + bias);
                hs[j] = hn;
                size_t o = (size_t)(bj0 + j) * NR + ncol;
                stH(hwr + o, (_Float16)hn);                    // LLC write-through publish
                if (ROLE == 1)
                    __builtin_nontemporal_store(hn, out + (size_t)t * NBNR + o);
                if (t == S_LEN - 1)
                    __builtin_nontemporal_store(hn, hn_base + o);
            }
        }
        if (s < S_LEN) gbar(bar);
    }
}

// blocks 0..63: layer 0 (step s); blocks 64..127: layer 1 (step s-1)
__global__ void __launch_bounds__(TPB, 2) esn_kernel(
    const float* __restrict__ b0v, const float* __restrict__ b1v,
    const float* __restrict__ Whh0, const float* __restrict__ Win0,
    const float* __restrict__ Whh1, const float* __restrict__ Win1,
    const _Float16* __restrict__ xf,
    _Float16* __restrict__ h0p, _Float16* __restrict__ h1p,
    unsigned* __restrict__ bar, float* __restrict__ out)
{
    __shared__ __align__(16) float rsc[64 * 64 * 4];   // 64 KiB reduction scratch
    const int bid = blockIdx.x;
    if (bid < LBLK)
        esn_layer_run<(NR + NI) / 32 / 8, NI, 0>(b0v, Whh0, Win0, xf, h0p, nullptr,
                                                 out, bar, rsc, bid * FPB);
    else
        esn_layer_run<(NR + NR) / 32 / 8, NR, 1>(b1v, Whh1, Win1, nullptr, h1p, h0p,
                                                 out, bar, rsc, (bid - LBLK) * FPB);
}

extern "C" void kernel_launch(void* const* d_in, const int* in_sizes, int n_in,
                              void* d_out, int out_size, void* d_ws, size_t ws_size,
                              hipStream_t stream) {
    const float* x    = (const float*)d_in[0];
    const float* Win0 = (const float*)d_in[1];
    const float* Whh0 = (const float*)d_in[2];
    const float* b0   = (const float*)d_in[3];
    const float* Win1 = (const float*)d_in[4];
    const float* Whh1 = (const float*)d_in[5];
    const float* b1   = (const float*)d_in[6];

    char* ws = (char*)d_ws;
    _Float16* xf  = (_Float16*)(ws + OFF_XF);
    _Float16* h0p = (_Float16*)(ws + OFF_H0);
    _Float16* h1p = (_Float16*)(ws + OFF_H1);
    unsigned* bar = (unsigned*)(ws + OFF_BAR);
    float* out = (float*)d_out;

    // zero barrier + both h ping-pong pairs
    hipMemsetAsync(ws, 0, OFF_XF, stream);

    xconv_kernel<<<dim3((S_LEN * NB * NI) / (256 * 8)), dim3(256), 0, stream>>>(x, xf);

    void* args[] = { (void*)&b0, (void*)&b1, (void*)&Whh0, (void*)&Win0,
                     (void*)&Whh1, (void*)&Win1, (void*)&xf, (void*)&h0p,
                     (void*)&h1p, (void*)&bar, (void*)&out };
    hipError_t e = hipLaunchCooperativeKernel((void*)esn_kernel, dim3(NBLK), dim3(TPB),
                                              args, 0, stream);
    if (e != hipSuccess) {
        esn_kernel<<<dim3(NBLK), dim3(TPB), 0, stream>>>(
            b0, b1, Whh0, Win0, Whh1, Win1, xf, h0p, h1p, bar, out);
    }
}

// Round 5
// 8902.310 us; speedup vs baseline: 1.8492x; 1.8492x over previous
//
#include <hip/hip_runtime.h>

typedef _Float16 half8 __attribute__((ext_vector_type(8)));
typedef float floatx4 __attribute__((ext_vector_type(4)));

#define S_LEN 512
#define NB 64
#define NI 256
#define NR 2048
#define LEAK 0.9f

#define NBLK 128
#define TPB 512
#define LBLK 64
#define NBNR ((size_t)NB * NR)

// ---- workspace offsets ----
#define OFF_BAR ((size_t)0)
#define OFF_H0  ((size_t)4096)                 /* 2-parity fragment-order h exch, layer0 */
#define OFF_H1  (OFF_H0 + 2 * NBNR * 2)        /* layer1 */
#define OFF_XE  (OFF_H1 + 2 * NBNR * 2)        /* x in fragment order, per t */

__device__ __forceinline__ half8 cvt8(const float* s) {
    float4 p = *(const float4*)s, q = *(const float4*)(s + 4);
    half8 v;
    v[0] = (_Float16)p.x; v[1] = (_Float16)p.y; v[2] = (_Float16)p.z; v[3] = (_Float16)p.w;
    v[4] = (_Float16)q.x; v[5] = (_Float16)q.y; v[6] = (_Float16)q.z; v[7] = (_Float16)q.w;
    return v;
}

// x fp32 -> fp16 in fragment order: per t, 32 units of 1KB; unit u=(bt*8+c),
// element (l*8+e) <-> (batch=bt*16+(l&15), i=c*32+(l>>4)*8+e)
__global__ void xprep_kernel(const float* __restrict__ x, _Float16* __restrict__ xe) {
    const int t = blockIdx.x;
    #pragma unroll
    for (int it = 0; it < 4; ++it) {
        const int u = it * 8 + (threadIdx.x >> 6);
        const int l = threadIdx.x & 63;
        const int b = (u >> 3) * 16 + (l & 15);
        const int i0 = (u & 7) * 32 + (l >> 4) * 8;
        half8 v = cvt8(x + ((size_t)t * NB + b) * NI + i0);
        *(half8*)(xe + (size_t)t * NB * NI + (size_t)u * 512 + (size_t)l * 8) = v;
    }
}

// two-level grid barrier with release/acquire fences (R3-proven)
__device__ __forceinline__ void gbar(unsigned* bar) {
    __syncthreads();                       // drains each wave's vmcnt
    if (threadIdx.x == 0) {
        __threadfence();                   // release: L2 writeback
        unsigned* cnt  = bar + (blockIdx.x & 7) * 32;
        unsigned* root = bar + 256;
        unsigned* gen  = bar + 272;
        unsigned g = __hip_atomic_load(gen, __ATOMIC_RELAXED, __HIP_MEMORY_SCOPE_AGENT);
        bool last = false;
        if (__hip_atomic_fetch_add(cnt, 1u, __ATOMIC_ACQ_REL, __HIP_MEMORY_SCOPE_AGENT) == (NBLK / 8 - 1)) {
            __hip_atomic_store(cnt, 0u, __ATOMIC_RELAXED, __HIP_MEMORY_SCOPE_AGENT);
            if (__hip_atomic_fetch_add(root, 1u, __ATOMIC_ACQ_REL, __HIP_MEMORY_SCOPE_AGENT) == 7u) {
                __hip_atomic_store(root, 0u, __ATOMIC_RELAXED, __HIP_MEMORY_SCOPE_AGENT);
                __hip_atomic_store(gen, g + 1u, __ATOMIC_RELEASE, __HIP_MEMORY_SCOPE_AGENT);
                last = true;
            }
        }
        if (!last)
            while (__hip_atomic_load(gen, __ATOMIC_RELAXED, __HIP_MEMORY_SCOPE_AGENT) == g)
                __builtin_amdgcn_s_sleep(1);
        __threadfence();                   // acquire: cache invalidate
    }
    __syncthreads();
}

// One layer, persistent. 8 waves per block; wave w owns k-chunks {w*8+j}.
// h exchange buffers are in MFMA fragment order: unit (bt*64+chunk) * 1024B,
// within-unit byte = lane*16 -> A-load is one contiguous 1KB global_load per chunk.
template <int CH, int KU, int ROLE>
__device__ __forceinline__ void esn_layer_run(
    const float* __restrict__ bias_v,
    const float* __restrict__ Whh, const float* __restrict__ Win,
    const char* __restrict__ xe,       // ROLE 0: x exchange (fragment order)
    char* __restrict__ hp,             // own h exchange ping-pong
    const char* __restrict__ h0p,      // ROLE 1: producer (y0) exchange
    float* __restrict__ out,
    unsigned* __restrict__ bar,
    float* __restrict__ rsc, int r0)
{
    const int tid = threadIdx.x;
    const int l = tid & 63, w = tid >> 6, l15 = l & 15, g = l >> 4;

    // ---- weights for this wave's chunks into registers (once) ----
    half8 bwA[CH], bwB[CH];
    #pragma unroll
    for (int j = 0; j < CH; ++j) {
        const float* s0; int rs;
        if (j < 8) { s0 = Whh + (size_t)(r0 + l15) * NR + (w * 8 + j) * 32 + g * 8; rs = NR; }
        else if (ROLE == 0) { s0 = Win + (size_t)(r0 + l15) * KU + w * 32 + g * 8; rs = KU; }
        else { s0 = Win + (size_t)(r0 + l15) * KU + (w * 8 + j - 8) * 32 + g * 8; rs = KU; }
        bwA[j] = cvt8(s0);
        bwB[j] = cvt8(s0 + (size_t)16 * rs);
    }

    const int fg_o = w & 1, bt_o = w >> 1;
    const int ncol = r0 + fg_o * 16 + l15;
    const int bj0 = bt_o * 16 + g * 4;
    const float bias = bias_v[ncol];
    const int cu = ncol >> 5, gg = (ncol >> 3) & 3, ee = ncol & 7;
    float hs[4] = {0.f, 0.f, 0.f, 0.f};
    float* hn_base = out + (size_t)S_LEN * NBNR + (size_t)ROLE * NBNR;

    for (int s = 0; s < S_LEN + 1; ++s) {
        const int t = (ROLE == 0) ? s : s - 1;
        const bool active = (ROLE == 0) ? (s < S_LEN) : (s >= 1);
        if (active) {
            const char* hu = hp + (size_t)(t & 1) * (NBNR * 2);
            const char* uu = (ROLE == 0) ? xe + (size_t)t * NB * NI * 2
                                         : h0p + (size_t)((t + 1) & 1) * (NBNR * 2);

            floatx4 acc[2][4];
            #pragma unroll
            for (int fg = 0; fg < 2; ++fg)
                #pragma unroll
                for (int bt = 0; bt < 4; ++bt)
                    acc[fg][bt] = (floatx4){0.f, 0.f, 0.f, 0.f};

            #pragma unroll
            for (int bt = 0; bt < 4; ++bt) {
                half8 abuf[CH];
                #pragma unroll
                for (int j = 0; j < CH; ++j) {
                    const char* src; size_t unit;
                    if (j < 8)          { src = hu; unit = (size_t)(bt * 64 + w * 8 + j); }
                    else if (ROLE == 0) { src = uu; unit = (size_t)(bt * 8 + w); }
                    else                { src = uu; unit = (size_t)(bt * 64 + w * 8 + j - 8); }
                    abuf[j] = *(const half8*)(src + unit * 1024 + (size_t)l * 16);
                }
                #pragma unroll
                for (int j = 0; j < CH; ++j) {
                    acc[0][bt] = __builtin_amdgcn_mfma_f32_16x16x32_f16(abuf[j], bwA[j], acc[0][bt], 0, 0, 0);
                    acc[1][bt] = __builtin_amdgcn_mfma_f32_16x16x32_f16(abuf[j], bwB[j], acc[1][bt], 0, 0, 0);
                }
            }

            // cross-wave K reduction through LDS (contiguous 16B/lane, conflict-free)
            #pragma unroll
            for (int fg = 0; fg < 2; ++fg)
                #pragma unroll
                for (int bt = 0; bt < 4; ++bt)
                    *(floatx4*)(rsc + (size_t)((w * 8 + fg * 4 + bt) * 64 + l) * 4) = acc[fg][bt];
            __syncthreads();

            floatx4 r = {0.f, 0.f, 0.f, 0.f};
            #pragma unroll
            for (int v = 0; v < 8; ++v)
                r += *(const floatx4*)(rsc + (size_t)((v * 8 + fg_o * 4 + bt_o) * 64 + l) * 4);

            char* hw = hp + (size_t)((t + 1) & 1) * (NBNR * 2);
            #pragma unroll
            for (int j = 0; j < 4; ++j) {
                float hn = (1.0f - LEAK) * hs[j] + LEAK * tanhf(r[j] + bias);
                hs[j] = hn;
                const int bj = bj0 + j;
                // fragment-order publish
                size_t byte = (size_t)((bj >> 4) * 64 + cu) * 1024
                            + (size_t)((gg * 16 + (bj & 15)) * 8 + ee) * 2;
                *(_Float16*)(hw + byte) = (_Float16)hn;
                if (ROLE == 1)
                    __builtin_nontemporal_store(hn, out + (size_t)t * NBNR + (size_t)bj * NR + ncol);
                if (t == S_LEN - 1)
                    __builtin_nontemporal_store(hn, hn_base + (size_t)bj * NR + ncol);
            }
        }
        if (s < S_LEN) gbar(bar);
    }
}

// blocks 0..63: layer 0 (step s); blocks 64..127: layer 1 (step s-1)
__global__ void __launch_bounds__(TPB, 1) esn_kernel(
    const float* __restrict__ b0v, const float* __restrict__ b1v,
    const float* __restrict__ Whh0, const float* __restrict__ Win0,
    const float* __restrict__ Whh1, const float* __restrict__ Win1,
    const char* __restrict__ xe,
    char* __restrict__ h0p, char* __restrict__ h1p,
    unsigned* __restrict__ bar, float* __restrict__ out)
{
    __shared__ __align__(16) float rsc[64 * 64 * 4];   // 64 KiB reduction scratch
    const int bid = blockIdx.x;
    if (bid < LBLK)
        esn_layer_run<9, NI, 0>(b0v, Whh0, Win0, xe, h0p, nullptr,
                                out, bar, rsc, bid * 32);
    else
        esn_layer_run<16, NR, 1>(b1v, Whh1, Win1, nullptr, h1p, h0p,
                                 out, bar, rsc, (bid - LBLK) * 32);
}

extern "C" void kernel_launch(void* const* d_in, const int* in_sizes, int n_in,
                              void* d_out, int out_size, void* d_ws, size_t ws_size,
                              hipStream_t stream) {
    const float* x    = (const float*)d_in[0];
    const float* Win0 = (const float*)d_in[1];
    const float* Whh0 = (const float*)d_in[2];
    const float* b0   = (const float*)d_in[3];
    const float* Win1 = (const float*)d_in[4];
    const float* Whh1 = (const float*)d_in[5];
    const float* b1   = (const float*)d_in[6];

    char* ws = (char*)d_ws;
    char* xe  = ws + OFF_XE;
    char* h0p = ws + OFF_H0;
    char* h1p = ws + OFF_H1;
    unsigned* bar = (unsigned*)(ws + OFF_BAR);
    float* out = (float*)d_out;

    // zero barrier + both fragment-order h exchanges (initial state h=0)
    hipMemsetAsync(ws, 0, OFF_XE, stream);

    xprep_kernel<<<dim3(S_LEN), dim3(512), 0, stream>>>(x, (_Float16*)xe);

    void* args[] = { (void*)&b0, (void*)&b1, (void*)&Whh0, (void*)&Win0,
                     (void*)&Whh1, (void*)&Win1, (void*)&xe, (void*)&h0p,
                     (void*)&h1p, (void*)&bar, (void*)&out };
    hipError_t e = hipLaunchCooperativeKernel((void*)esn_kernel, dim3(NBLK), dim3(TPB),
                                              args, 0, stream);
    if (e != hipSuccess) {
        esn_kernel<<<dim3(NBLK), dim3(TPB), 0, stream>>>(
            b0, b1, Whh0, Win0, Whh1, Win1, xe, h0p, h1p, bar, out);
    }
}